// Round 2
// baseline (182.112 us; speedup 1.0000x reference)
//
#include <hip/hip_runtime.h>

#define HW      (1024 * 1024)
#define HW4     (HW / 4)
#define NBINS   4096
#define NIMG    9                 // 8 input images + 1 style
#define BPI     128               // blocks per image
#define THREADS 256
#define F4_PER_BLOCK (HW4 / BPI)  // 2048 float4 elements per block per channel

// Exact replica of searchsorted(boundaries, x, side='left') with
// boundaries b_j = (j+1)*0.125 - 1 (j = 0..14), i.e. idx = #{ b_j < x }.
// Branchless binary search with exact float compares (all boundary values
// k/8 - 1 are exactly representable) -- verified absmax 0.0 in round 1.
__device__ __forceinline__ int bin16(float x) {
    int lo = 0;
    if (0.0f < x) lo = 8;                                    // b_7  = 0.0
    if ((float)(lo + 4) * 0.125f - 1.0f < x) lo += 4;
    if ((float)(lo + 2) * 0.125f - 1.0f < x) lo += 2;
    if ((float)(lo + 1) * 0.125f - 1.0f < x) lo += 1;
    return lo;                                               // in [0, 15]
}

__device__ __forceinline__ int bin3(float r, float g, float b) {
    return bin16(r) + 16 * bin16(g) + 256 * bin16(b);
}

__device__ __forceinline__ void acc4(int* lh, float4 r, float4 g, float4 b) {
    atomicAdd(&lh[bin3(r.x, g.x, b.x)], 1);
    atomicAdd(&lh[bin3(r.y, g.y, b.y)], 1);
    atomicAdd(&lh[bin3(r.z, g.z, b.z)], 1);
    atomicAdd(&lh[bin3(r.w, g.w, b.w)], 1);
}

// Each block builds a private LDS histogram and writes it (no atomics) to
// its own slice of part[NIMG][BPI][NBINS].
__global__ __launch_bounds__(THREADS) void hist_kernel(
        const float* __restrict__ input,   // [8,3,HW]
        const float* __restrict__ style,   // [1,3,HW]
        int* __restrict__ part) {          // [NIMG, BPI, NBINS]
    __shared__ int lh[NBINS];              // 16 KB
    const int img = blockIdx.y;
    const int blk = blockIdx.x;
    const float* base = (img < 8) ? (input + (size_t)img * 3 * HW) : style;

    for (int i = threadIdx.x; i < NBINS; i += THREADS) lh[i] = 0;
    __syncthreads();

    const float4* c0 = (const float4*)(base);
    const float4* c1 = (const float4*)(base + HW);
    const float4* c2 = (const float4*)(base + 2 * HW);
    const int start = blk * F4_PER_BLOCK;

    // 2048 float4/channel per block, 256 threads -> 8 iterations; unroll 2
    // so 6 float4 loads are in flight per macro-iteration.
    for (int j = threadIdx.x; j < F4_PER_BLOCK; j += 2 * THREADS) {
        const int p0 = start + j;
        const int p1 = p0 + THREADS;
        float4 r0 = c0[p0], g0 = c1[p0], b0 = c2[p0];
        float4 r1 = c0[p1], g1 = c1[p1], b1 = c2[p1];
        acc4(lh, r0, g0, b0);
        acc4(lh, r1, g1, b1);
    }
    __syncthreads();

    // Vectorized, atomic-free flush of the private histogram.
    int4* dst = (int4*)(part + ((size_t)img * BPI + blk) * NBINS);
    const int4* src = (const int4*)lh;
    for (int i = threadIdx.x; i < NBINS / 4; i += THREADS) dst[i] = src[i];
}

// H[img][bin] = sum over BPI partials. Grid (16 chunks, 9 imgs) x 256 thr.
__global__ __launch_bounds__(THREADS) void reduce_kernel(
        const int* __restrict__ part,      // [NIMG, BPI, NBINS]
        int* __restrict__ H) {             // [NIMG, NBINS]
    const int img = blockIdx.y;
    const int bin = blockIdx.x * THREADS + threadIdx.x;   // 16*256 = 4096
    const int* p = part + (size_t)img * BPI * NBINS + bin;
    int sum = 0;
#pragma unroll 8
    for (int b = 0; b < BPI; ++b) sum += p[(size_t)b * NBINS];
    H[img * NBINS + bin] = sum;
}

// loss = sum_{b,i} | H[b][i] - H[8][i] | / (HW * 8 * NBINS)  (integer-exact)
__global__ __launch_bounds__(1024) void loss_kernel(
        const int* __restrict__ H, float* __restrict__ out) {
    __shared__ long long partsum[16];
    const int* tgt = H + 8 * NBINS;
    long long acc = 0;
    for (int e = threadIdx.x; e < 8 * NBINS; e += 1024) {
        const int b = e >> 12;
        const int i = e & (NBINS - 1);
        const int d = H[b * NBINS + i] - tgt[i];
        acc += (d < 0) ? (long long)(-d) : (long long)d;
    }
    for (int off = 32; off; off >>= 1) acc += __shfl_down(acc, off, 64);
    const int lane = threadIdx.x & 63;
    const int wv   = threadIdx.x >> 6;
    if (lane == 0) partsum[wv] = acc;
    __syncthreads();
    if (wv == 0) {
        long long t = (lane < 16) ? partsum[lane] : 0;
        for (int off = 8; off; off >>= 1) t += __shfl_down(t, off, 64);
        if (lane == 0) {
            // divide by HW * 8 * NBINS = 2^20 * 2^3 * 2^12 = 2^35
            out[0] = (float)((double)t / 34359738368.0);
        }
    }
}

extern "C" void kernel_launch(void* const* d_in, const int* in_sizes, int n_in,
                              void* d_out, int out_size, void* d_ws, size_t ws_size,
                              hipStream_t stream) {
    const float* input = (const float*)d_in[0];  // [8,3,1024,1024]
    const float* style = (const float*)d_in[1];  // [1,3,1024,1024]
    int* part = (int*)d_ws;                      // [9][128][4096] = 18.9 MB
    int* H    = part + (size_t)NIMG * BPI * NBINS;  // [9][4096]

    hipLaunchKernelGGL(hist_kernel, dim3(BPI, NIMG), dim3(THREADS), 0, stream,
                       input, style, part);
    hipLaunchKernelGGL(reduce_kernel, dim3(NBINS / THREADS, NIMG), dim3(THREADS),
                       0, stream, part, H);
    hipLaunchKernelGGL(loss_kernel, dim3(1), dim3(1024), 0, stream,
                       H, (float*)d_out);
}